// Round 13
// baseline (45.361 us; speedup 1.0000x reference)
//
#include <hip/hip_runtime.h>
#include <cstdint>

#define B_ROWS 4096
#define N_ROWS 8192
#define D_DIM  256
#define BT     128                 // block tile 128x128
#define TGRID  64                  // 8192 / 128
#define NTILES 2080                // TGRID*(TGRID+1)/2
#define NPB    512                 // persistent blocks

typedef __attribute__((ext_vector_type(4))) float f32x4;
typedef __attribute__((ext_vector_type(2))) unsigned long u64x2;

__device__ __forceinline__ void gload16(const void* g, void* l) {
    __builtin_amdgcn_global_load_lds(
        (const __attribute__((address_space(1))) void*)g,
        (__attribute__((address_space(3))) void*)l, 16, 0, 0);
}

__device__ __forceinline__ f32x4 exp4(f32x4 v) {
    f32x4 r;
    r.x = __expf(v.x); r.y = __expf(v.y); r.z = __expf(v.z); r.w = __expf(v.w);
    return r;
}

// f32 -> fp8 e4m3fn (OCP), RNE, with subnormal support. |f| < 448 assumed.
__device__ __forceinline__ unsigned f2e4m3(float f) {
    union { float f; unsigned u; } v; v.f = f;
    unsigned s = (v.u >> 24) & 0x80u;
    unsigned mag = v.u & 0x7fffffffu;
    int e = (int)(mag >> 23) - 127;
    if (e >= -6) {  // normal range for e4m3
        unsigned r = mag + 0x7ffffu + ((mag >> 20) & 1u);   // RNE into 3 mantissa bits
        int e2 = (int)(r >> 23) - 127;
        unsigned m3 = (r >> 20) & 7u;
        return s | (unsigned)((e2 + 7) << 3) | m3;
    }
    if (e < -10) return s;                                   // underflow to 0
    float q = rintf(fabsf(f) * 512.0f);                      // subnormal: units of 2^-9
    unsigned qi = (unsigned)q;                               // 0..8
    return s | qi;                                           // qi==8 -> 0x08 == 2^-6 normal
}

// ------------- Kernel A: normalize pair rows -> fp8 zn (grouped layout) + pos dot -------------
// zn row layout (256 B): 4 K-groups of 64 B; group g, 16B unit y in [0,4):
//   bytes [g*64 + y*16 .. +8)  = k in [g*64 + y*8,      +8)
//   bytes [g*64 + y*16 + 8 ..) = k in [g*64 + 32 + y*8, +8)
__global__ __launch_bounds__(256) void normpos_kernel(const float* __restrict__ zi,
                                                      const float* __restrict__ zj,
                                                      unsigned char* __restrict__ zn,
                                                      float* __restrict__ pospartial) {
    int wid = threadIdx.x >> 6;
    int lane = threadIdx.x & 63;
    int p = blockIdx.x * 4 + wid;          // 0..B_ROWS-1
    f32x4 ga = *(const f32x4*)(zi + (size_t)p * D_DIM + lane * 4);
    f32x4 gb = *(const f32x4*)(zj + (size_t)p * D_DIM + lane * 4);
    float sa = ga.x * ga.x + ga.y * ga.y + ga.z * ga.z + ga.w * ga.w;
    float sb = gb.x * gb.x + gb.y * gb.y + gb.z * gb.z + gb.w * gb.w;
    #pragma unroll
    for (int m = 1; m < 64; m <<= 1) { sa += __shfl_xor(sa, m, 64); sb += __shfl_xor(sb, m, 64); }
    float fa = 1.41421356237309515f / fmaxf(sqrtf(sa), 1e-8f);
    float fb = 1.41421356237309515f / fmaxf(sqrtf(sb), 1e-8f);
    f32x4 na, nb;
    na.x = ga.x * fa; na.y = ga.y * fa; na.z = ga.z * fa; na.w = ga.w * fa;
    nb.x = gb.x * fb; nb.y = gb.y * fb; nb.z = gb.z * fb; nb.w = gb.w * fb;
    unsigned pa = f2e4m3(na.x) | (f2e4m3(na.y) << 8) | (f2e4m3(na.z) << 16) | (f2e4m3(na.w) << 24);
    unsigned pb = f2e4m3(nb.x) | (f2e4m3(nb.y) << 8) | (f2e4m3(nb.z) << 16) | (f2e4m3(nb.w) << 24);
    int bytepos = (lane >> 4) * 64 + ((lane >> 1) & 3) * 16 + ((lane >> 3) & 1) * 8 + 4 * (lane & 1);
    *(unsigned*)(zn + (size_t)p * 256 + bytepos) = pa;
    *(unsigned*)(zn + (size_t)(p + B_ROWS) * 256 + bytepos) = pb;
    float d = na.x * nb.x + na.y * nb.y + na.z * nb.z + na.w * nb.w;
    #pragma unroll
    for (int m = 1; m < 64; m <<= 1) d += __shfl_xor(d, m, 64);
    if (lane == 0) pospartial[p] = d;
}

// ------------- Kernel C: persistent fp8 GEMM, 1 barrier/step, stage-ahead pipeline -------------
// 512 persistent blocks, 4 waves (2x2), wave-tile 64x64, BK=64 (4 steps/tile), dbuf.
// Per step: sync -> issue stage(s+1) -> ds_read/MFMA(s). Stage latency hidden by MFMA.
// Tiles per block: xb+512r (r<4); blocks with xb%16==0 take extra tile 2048+xb/16.
__global__ __launch_bounds__(256, 2) void simclr_gemm_kernel(const unsigned char* __restrict__ zn,
                                                             float* __restrict__ P) {
    __shared__ unsigned char As[2][8192];   // 2 x 8 KB (128 rows x 64 B)
    __shared__ unsigned char Bs[2][8192];
    __shared__ float rPpart[2][BT];
    __shared__ float cPpart[2][BT];

    const int tid = threadIdx.x;
    const int lane = tid & 63, wid = tid >> 6;
    const int wr = wid >> 1, wc = wid & 1;      // 2x2 wave grid

    // XCD-bijective chunked swizzle over persistent blocks (512 = 8 x 64)
    const int xb = (int)((blockIdx.x & 7) * (NPB / 8) + (blockIdx.x >> 3));
    const int nt = 4 + ((xb & 15) == 0 ? 1 : 0);

    const int r0 = tid >> 2;
    const int sch = (tid & 3) ^ ((tid >> 3) & 3);
    const size_t gof0 = (size_t)r0 * 256 + (size_t)sch * 16;
    const size_t gof1 = (size_t)(64 + r0) * 256 + (size_t)sch * 16;
    const unsigned lo0 = (unsigned)tid * 16;
    const unsigned lo1 = 4096u + (unsigned)tid * 16;

    const int ysw = (lane >> 4) ^ (((lane & 15) >> 1) & 3);
    const int arow = wr * 64 + (lane & 15);
    const int brow = wc * 64 + (lane & 15);

#define TILE_OF(r_)  (((r_) < 4) ? (xb + ((r_) << 9)) : (2048 + (xb >> 4)))
#define DECODE(t_, ti_, tj_) do {                                              \
    int a_ = (int)((129.0f - sqrtf(16641.0f - 8.0f * (float)(t_))) * 0.5f);    \
    while ((a_ + 1) * TGRID - ((a_ + 1) * a_) / 2 <= (t_)) ++a_;               \
    while (a_ * TGRID - (a_ * (a_ - 1)) / 2 > (t_)) --a_;                      \
    (ti_) = a_; (tj_) = a_ + ((t_) - (a_ * TGRID - (a_ * (a_ - 1)) / 2));      \
} while (0)
#define STAGE(buf_, gA_, gB_, kt_) do {                                        \
    size_t kb_ = (size_t)(kt_) * 64;                                           \
    gload16((gA_) + gof0 + kb_, &As[buf_][lo0]);                               \
    gload16((gA_) + gof1 + kb_, &As[buf_][lo1]);                               \
    gload16((gB_) + gof0 + kb_, &Bs[buf_][lo0]);                               \
    gload16((gB_) + gof1 + kb_, &Bs[buf_][lo1]);                               \
} while (0)

    int ti, tj, ti_n, tj_n;
    DECODE(TILE_OF(0), ti, tj);
    const char* gAc = (const char*)zn + (size_t)ti * BT * 256;
    const char* gBc = (const char*)zn + (size_t)tj * BT * 256;
    const char* gAn = gAc;
    const char* gBn = gBc;
    const int S = 4 * nt;

    STAGE(0, gAc, gBc, 0);                       // step 0 prefetch

    for (int r = 0; r < nt; ++r) {
        f32x4 acc[4][4];
        #pragma unroll
        for (int m = 0; m < 4; ++m)
            #pragma unroll
            for (int n = 0; n < 4; ++n)
                acc[m][n] = (f32x4){0.f, 0.f, 0.f, 0.f};

        #pragma unroll
        for (int kt = 0; kt < 4; ++kt) {
            const int s = 4 * r + kt;
            __syncthreads();                     // buf s&1 data visible; buf (s+1)&1 free
            if (s + 1 < S) {
                const int kt2 = (s + 1) & 3;
                if (kt2 == 0) {                  // next tile's first step
                    DECODE(TILE_OF(r + 1), ti_n, tj_n);
                    gAn = (const char*)zn + (size_t)ti_n * BT * 256;
                    gBn = (const char*)zn + (size_t)tj_n * BT * 256;
                    STAGE((s + 1) & 1, gAn, gBn, 0);
                } else {
                    STAGE((s + 1) & 1, gAc, gBc, kt2);
                }
            }
            // compute on buf s&1 (stage above has the whole MFMA phase to land)
            u64x2 af[4], bfr[4];
            #pragma unroll
            for (int m = 0; m < 4; ++m)
                af[m] = *(const u64x2*)&As[s & 1][(arow + m * 16) * 64 + ysw * 16];
            #pragma unroll
            for (int n = 0; n < 4; ++n)
                bfr[n] = *(const u64x2*)&Bs[s & 1][(brow + n * 16) * 64 + ysw * 16];
            #pragma unroll
            for (int m = 0; m < 4; ++m)
                #pragma unroll
                for (int n = 0; n < 4; ++n) {
                    acc[m][n] = __builtin_amdgcn_mfma_f32_16x16x32_fp8_fp8(
                        (long)af[m].x, (long)bfr[n].x, acc[m][n], 0, 0, 0);
                    acc[m][n] = __builtin_amdgcn_mfma_f32_16x16x32_fp8_fp8(
                        (long)af[m].y, (long)bfr[n].y, acc[m][n], 0, 0, 0);
                }
        }

        // ---- epilogue for tile (ti, tj): exp + unique-writer LDS partials ----
        float cs[4] = {0.f, 0.f, 0.f, 0.f};
        #pragma unroll
        for (int m = 0; m < 4; ++m) {
            f32x4 ef[4];
            #pragma unroll
            for (int n = 0; n < 4; ++n) ef[n] = exp4(acc[m][n]);
            f32x4 rv = ef[0] + ef[1] + ef[2] + ef[3];
            #pragma unroll
            for (int msk = 1; msk <= 8; msk <<= 1) {
                rv.x += __shfl_xor(rv.x, msk, 64);
                rv.y += __shfl_xor(rv.y, msk, 64);
                rv.z += __shfl_xor(rv.z, msk, 64);
                rv.w += __shfl_xor(rv.w, msk, 64);
            }
            if ((lane & 15) == 0) {
                int rbase = wr * 64 + m * 16 + (lane >> 4) * 4;
                rPpart[wc][rbase + 0] = rv.x;
                rPpart[wc][rbase + 1] = rv.y;
                rPpart[wc][rbase + 2] = rv.z;
                rPpart[wc][rbase + 3] = rv.w;
            }
            #pragma unroll
            for (int n = 0; n < 4; ++n)
                cs[n] += ef[n].x + ef[n].y + ef[n].z + ef[n].w;
        }
        #pragma unroll
        for (int n = 0; n < 4; ++n) {
            float c = cs[n];
            c += __shfl_xor(c, 16, 64);
            c += __shfl_xor(c, 32, 64);
            if (lane < 16) cPpart[wr][wc * 64 + n * 16 + lane] = c;
        }
        __syncthreads();                         // partials visible (also drains next-tile stage0)

        if (tid < BT) {
            P[(size_t)tj * N_ROWS + ti * BT + tid] = rPpart[0][tid] + rPpart[1][tid];
        } else if (ti != tj) {
            int t = tid - BT;
            P[(size_t)ti * N_ROWS + tj * BT + t] = cPpart[0][t] + cPpart[1][t];
        }

        ti = ti_n; tj = tj_n; gAc = gAn; gBc = gBn;
    }
#undef STAGE
#undef DECODE
#undef TILE_OF
}

// ------------- Kernel E: per-row reduce over 64 slots + log (+fold pos) -------------
__global__ __launch_bounds__(256) void reduce_rows_kernel(const float* __restrict__ P,
                                                          const float* __restrict__ pospartial,
                                                          float* __restrict__ blockpart) {
    const float E2 = 7.38905609893065f;   // exp(self-sim) = e^2
    int row = blockIdx.x * 256 + threadIdx.x;
    float s = 0.f;
    #pragma unroll 16
    for (int src = 0; src < TGRID; ++src)
        s += P[(size_t)src * N_ROWS + row];
    float v = logf(s - E2);
    if (threadIdx.x < 128)
        v -= 2.0f * pospartial[blockIdx.x * 128 + threadIdx.x];
    #pragma unroll
    for (int m = 1; m < 64; m <<= 1) v += __shfl_xor(v, m, 64);
    __shared__ float ws[4];
    if ((threadIdx.x & 63) == 0) ws[threadIdx.x >> 6] = v;
    __syncthreads();
    if (threadIdx.x == 0) blockpart[blockIdx.x] = ws[0] + ws[1] + ws[2] + ws[3];
}

// ------------- Kernel F: out = sum(blockpart) / N -------------
__global__ __launch_bounds__(64) void final_kernel(const float* __restrict__ blockpart,
                                                   float* __restrict__ out) {
    int lane = threadIdx.x;
    float v = (lane < 32) ? blockpart[lane] : 0.f;
    #pragma unroll
    for (int m = 1; m < 64; m <<= 1) v += __shfl_xor(v, m, 64);
    if (lane == 0) out[0] = v / (float)N_ROWS;
}

extern "C" void kernel_launch(void* const* d_in, const int* in_sizes, int n_in,
                              void* d_out, int out_size, void* d_ws, size_t ws_size,
                              hipStream_t stream) {
    const float* zi = (const float*)d_in[0];
    const float* zj = (const float*)d_in[1];
    char* ws = (char*)d_ws;
    unsigned char* zn = (unsigned char*)ws;                          // 2 MB (8192 x 256 B)
    float* P = (float*)(ws + 2 * 1024 * 1024);                       // 2 MB (64 x 8192 f32)
    float* pospartial = (float*)(ws + 4 * 1024 * 1024);              // 16 KB
    float* blockpart = (float*)(ws + 4 * 1024 * 1024 + 16 * 1024);   // 128 B

    normpos_kernel<<<B_ROWS / 4, 256, 0, stream>>>(zi, zj, zn, pospartial);
    simclr_gemm_kernel<<<NPB, 256, 0, stream>>>(zn, P);
    reduce_rows_kernel<<<N_ROWS / 256, 256, 0, stream>>>(P, pospartial, blockpart);
    final_kernel<<<1, 64, 0, stream>>>(blockpart, (float*)d_out);
}